// Round 6
// baseline (188.073 us; speedup 1.0000x reference)
//
#include <hip/hip_runtime.h>

#define BS 64
#define C 512
#define DIN 256
#define DOUT 256
#define H 4
#define HD 64

typedef __attribute__((ext_vector_type(8))) short short8;
typedef __attribute__((ext_vector_type(4))) float f32x4;

__device__ __forceinline__ short f2bf(float f) {
    union { float f; unsigned u; } v; v.f = f;
    unsigned r = v.u + 0x7fffu + ((v.u >> 16) & 1u);
    return (short)(r >> 16);
}

__device__ __forceinline__ short8 pack8(const float* p) {
    short8 r;
#pragma unroll
    for (int i = 0; i < 8; ++i) r[i] = f2bf(p[i]);
    return r;
}

// pack to bf16 AND accumulate the sum of the ROUNDED values (numerator/denominator
// of the softmax share identical rounding -> uniform error cancels)
__device__ __forceinline__ short8 pack8_sum(const float* p, float& s) {
    short8 r;
#pragma unroll
    for (int i = 0; i < 8; ++i) {
        const short b = f2bf(p[i]);
        r[i] = b;
        union { unsigned u; float f; } v;
        v.u = ((unsigned)(unsigned short)b) << 16;
        s += v.f;
    }
    return r;
}

// K1: Wh = h @ W^T (bf16 MFMA), store WhT[b][h][d][c] bf16 + e_i/e_j[b][h][c] f32
__global__ __launch_bounds__(256) void k1_gemm(
    const float* __restrict__ hsrc, const float* __restrict__ W,
    const float* __restrict__ avec,
    short* __restrict__ whT, float* __restrict__ ei, float* __restrict__ ej)
{
    const int tid = threadIdx.x;
    const int l = tid & 63;
    const int w = tid >> 6;
    const int mtile = blockIdx.x >> 1;
    const int ntile = blockIdx.x & 1;
    const int row_base = mtile * 64 + (w & 1) * 32;     // global row in [0,32768)
    const int col_base = ntile * 128 + (w >> 1) * 64;   // output col in [0,256)
    const int head = col_base >> 6;
    const int lr = l & 15;
    const int kg = (l >> 4) * 8;

    f32x4 acc[2][4];
#pragma unroll
    for (int i = 0; i < 2; ++i)
#pragma unroll
        for (int j = 0; j < 4; ++j) acc[i][j] = f32x4{0.f, 0.f, 0.f, 0.f};

    for (int k0 = 0; k0 < DIN; k0 += 32) {
        short8 af[2];
#pragma unroll
        for (int rt = 0; rt < 2; ++rt) {
            const float* p = hsrc + (size_t)(row_base + rt * 16 + lr) * DIN + k0 + kg;
            float tmp[8];
            *(float4*)(tmp)     = *(const float4*)(p);
            *(float4*)(tmp + 4) = *(const float4*)(p + 4);
            af[rt] = pack8(tmp);
        }
        short8 bfr[4];
#pragma unroll
        for (int ct = 0; ct < 4; ++ct) {
            const float* p = W + (size_t)(col_base + ct * 16 + lr) * DIN + k0 + kg;
            float tmp[8];
            *(float4*)(tmp)     = *(const float4*)(p);
            *(float4*)(tmp + 4) = *(const float4*)(p + 4);
            bfr[ct] = pack8(tmp);
        }
#pragma unroll
        for (int rt = 0; rt < 2; ++rt)
#pragma unroll
            for (int ct = 0; ct < 4; ++ct)
                acc[rt][ct] = __builtin_amdgcn_mfma_f32_16x16x32_bf16(
                    af[rt], bfr[ct], acc[rt][ct], 0, 0, 0);
    }

    float avi[4], avj[4];
#pragma unroll
    for (int ct = 0; ct < 4; ++ct) {
        avi[ct] = avec[head * 2 * HD + ct * 16 + lr];
        avj[ct] = avec[head * 2 * HD + HD + ct * 16 + lr];
    }
#pragma unroll
    for (int rt = 0; rt < 2; ++rt) {
#pragma unroll
        for (int reg = 0; reg < 4; ++reg) {
            const int crow = row_base + rt * 16 + (l >> 4) * 4 + reg;
            const int b = crow >> 9;
            const int c = crow & 511;
            float pi = 0.f, pj = 0.f;
#pragma unroll
            for (int ct = 0; ct < 4; ++ct) {
                const float v = acc[rt][ct][reg];
                pi += v * avi[ct];
                pj += v * avj[ct];
                const int d = ct * 16 + lr;
                whT[((size_t)(b * H + head) * HD + d) * C + c] = f2bf(v);
            }
#pragma unroll
            for (int off = 1; off < 16; off <<= 1) {
                pi += __shfl_xor(pi, off);
                pj += __shfl_xor(pj, off);
            }
            if (lr == 0) {
                ei[(b * H + head) * C + c] = pi;
                ej[(b * H + head) * C + c] = pj;
            }
        }
    }
}

// K2: per (b, 16-row i-tile) block; wave = head. Grid 2048 -> 8192 waves (100% of
// wave slots at <=64 VGPR). Non-online softmax (scores bounded), lean registers:
// process j in 8-element halves, V loaded per-dt.
__global__ __launch_bounds__(256, 8) void k2_attn(
    const float* __restrict__ Afc, const short* __restrict__ whT,
    const float* __restrict__ ei, const float* __restrict__ ej,
    float* __restrict__ hp)
{
    const int tid = threadIdx.x;
    const int l = tid & 63;
    const int hh = tid >> 6;
    // nwg=2048, 8 XCDs, 256 blocks/XCD: swz = (bid%8)*256 + bid/8 (bijective);
    // each XCD owns 8 whole b's -> whT/Afc stay XCD-L2-local.
    const int swz = (blockIdx.x & 7) * 256 + (blockIdx.x >> 3);
    const int b = swz >> 5;
    const int i0 = (swz & 31) * 16;
    const int lr = l & 15;
    const int kg = (l >> 4) * 8;
    const float L2E = 1.44269504088896f;

    f32x4 O[4];
#pragma unroll
    for (int dt = 0; dt < 4; ++dt) O[dt] = f32x4{0.f, 0.f, 0.f, 0.f};
    float lsum = 0.f;

    const float eiv = ei[(b * H + hh) * C + i0 + lr] * L2E;
    const float* ejb = ej + (b * H + hh) * C;
    const short* vb = whT + (size_t)(b * H + hh) * HD * C;
    const float* ap = Afc + ((size_t)b * C + i0 + lr) * C;

    for (int jt = 0; jt < 8; ++jt) {
        const int j0 = jt * 64;
        short8 pa[2];
#pragma unroll
        for (int half = 0; half < 2; ++half) {
            const int jb = j0 + half * 32 + kg;
            float av[8];
            *(float4*)(av)     = *(const float4*)(ap + jb);
            *(float4*)(av + 4) = *(const float4*)(ap + jb + 4);
            float ejv[8];
            *(float4*)(ejv)     = *(const float4*)(ejb + jb);
            *(float4*)(ejv + 4) = *(const float4*)(ejb + jb + 4);
#pragma unroll
            for (int t = 0; t < 8; ++t) {
                // eiv/ejv carry log2(e); leaky_relu is positively homogeneous
                const float z = eiv + ejv[t] * L2E;
                const float zl = fmaxf(z, 0.2f * z);
                av[t] = exp2f(zl * av[t]);
            }
            pa[half] = pack8_sum(av, lsum);
        }
#pragma unroll
        for (int dt = 0; dt < 4; ++dt) {
            const short* vp = vb + (size_t)(dt * 16 + lr) * C + j0 + kg;
            const short8 vf0 = *(const short8*)(vp);
            const short8 vf1 = *(const short8*)(vp + 32);
            O[dt] = __builtin_amdgcn_mfma_f32_16x16x32_bf16(pa[0], vf0, O[dt], 0, 0, 0);
            O[dt] = __builtin_amdgcn_mfma_f32_16x16x32_bf16(pa[1], vf1, O[dt], 0, 0, 0);
        }
    }

    lsum += __shfl_xor(lsum, 16);
    lsum += __shfl_xor(lsum, 32);
    const float inv = 1.0f / lsum;
    float fr[4];
#pragma unroll
    for (int reg = 0; reg < 4; ++reg)
        fr[reg] = __shfl(inv, (l >> 4) * 4 + reg);
#pragma unroll
    for (int dt = 0; dt < 4; ++dt)
#pragma unroll
        for (int reg = 0; reg < 4; ++reg) {
            const int c = i0 + (l >> 4) * 4 + reg;
            hp[((size_t)b * C + c) * DOUT + hh * HD + dt * 16 + lr] =
                O[dt][reg] * fr[reg];
        }
}

// K3: s[c] = tanh(h_prime[c] @ W1^T + b1) @ W2^T + b2 — MFMA GEMM, no LDS.
__global__ __launch_bounds__(256) void k3_gate(
    const float* __restrict__ hp, const float* __restrict__ W1,
    const float* __restrict__ b1, const float* __restrict__ W2,
    const float* __restrict__ b2, float* __restrict__ sgate)
{
    const int t = threadIdx.x;
    const int l = t & 63;
    const int w = t >> 6;
    const int b = blockIdx.x >> 3;
    const int c0 = (blockIdx.x & 7) * 64;
    const int lr = l & 15;
    const int kg = (l >> 4) * 8;

    f32x4 acc[4];
#pragma unroll
    for (int ct = 0; ct < 4; ++ct) acc[ct] = f32x4{0.f, 0.f, 0.f, 0.f};

    const float* arow = hp + (size_t)(b * C + c0 + w * 16 + lr) * DOUT;
    for (int k0 = 0; k0 < DOUT; k0 += 32) {
        float ta[8];
        *(float4*)(ta)     = *(const float4*)(arow + k0 + kg);
        *(float4*)(ta + 4) = *(const float4*)(arow + k0 + kg + 4);
        const short8 af = pack8(ta);
#pragma unroll
        for (int ct = 0; ct < 4; ++ct) {
            const float* bp = W1 + (size_t)(ct * 16 + lr) * DOUT + k0 + kg;
            float tb[8];
            *(float4*)(tb)     = *(const float4*)(bp);
            *(float4*)(tb + 4) = *(const float4*)(bp + 4);
            acc[ct] = __builtin_amdgcn_mfma_f32_16x16x32_bf16(af, pack8(tb), acc[ct], 0, 0, 0);
        }
    }

    float b1v[4], w2v[4];
#pragma unroll
    for (int ct = 0; ct < 4; ++ct) {
        b1v[ct] = b1[ct * 16 + lr];
        w2v[ct] = W2[ct * 16 + lr];
    }
    const float b2v = b2[0];
#pragma unroll
    for (int reg = 0; reg < 4; ++reg) {
        float val = 0.f;
#pragma unroll
        for (int ct = 0; ct < 4; ++ct)
            val += tanhf(acc[ct][reg] + b1v[ct]) * w2v[ct];
#pragma unroll
        for (int off = 1; off < 16; off <<= 1) val += __shfl_xor(val, off);
        if (lr == 0)
            sgate[b * C + c0 + w * 16 + (l >> 4) * 4 + reg] = val + b2v;
    }
}

// K4a: per (b, 64-channel chunk): redundant block softmax over sgate + weighted
// partial sum of hp rows (coalesced). 512 blocks.
__global__ __launch_bounds__(256) void k4a_partial(
    const float* __restrict__ hp, const float* __restrict__ sgate,
    float* __restrict__ partial)
{
    __shared__ float red[16];
    __shared__ float wlds[64];
    const int t = threadIdx.x;
    const int b = blockIdx.x >> 3;
    const int c0 = (blockIdx.x & 7) * 64;
    const int l = t & 63, w = t >> 6;
    const float L2E = 1.44269504088896f;

    const float s0 = sgate[b * C + t], s1 = sgate[b * C + 256 + t];
    float mx = fmaxf(s0, s1);
#pragma unroll
    for (int off = 1; off < 64; off <<= 1) mx = fmaxf(mx, __shfl_xor(mx, off));
    if (l == 0) red[w] = mx;
    __syncthreads();
    mx = fmaxf(fmaxf(red[0], red[1]), fmaxf(red[2], red[3]));
    float sum = exp2f((s0 - mx) * L2E) + exp2f((s1 - mx) * L2E);
#pragma unroll
    for (int off = 1; off < 64; off <<= 1) sum += __shfl_xor(sum, off);
    if (l == 0) red[8 + w] = sum;
    __syncthreads();
    sum = red[8] + red[9] + red[10] + red[11];
    const float inv = 1.f / sum;
    if (t < 64)
        wlds[t] = exp2f((sgate[b * C + c0 + t] - mx) * L2E) * inv;
    __syncthreads();

    float acc = 0.f;
    const float* base = hp + ((size_t)b * C + c0) * DOUT + t;
#pragma unroll 4
    for (int c = 0; c < 64; ++c) acc += wlds[c] * base[(size_t)c * DOUT];
    partial[(size_t)blockIdx.x * DOUT + t] = acc;
}

// K4b: reduce the 8 chunk-partials per batch -> f32 out
__global__ __launch_bounds__(256) void k4b_reduce(
    const float* __restrict__ partial, float* __restrict__ out)
{
    const int t = threadIdx.x;
    const int b = blockIdx.x;
    float s = 0.f;
#pragma unroll
    for (int k = 0; k < 8; ++k)
        s += partial[(size_t)(b * 8 + k) * DOUT + t];
    out[b * DOUT + t] = s;
}

extern "C" void kernel_launch(void* const* d_in, const int* in_sizes, int n_in,
                              void* d_out, int out_size, void* d_ws, size_t ws_size,
                              hipStream_t stream) {
    const float* hsrc = (const float*)d_in[0];
    const float* Afc  = (const float*)d_in[1];
    const float* W    = (const float*)d_in[2];
    const float* avec = (const float*)d_in[3];
    const float* W1   = (const float*)d_in[4];
    const float* b1   = (const float*)d_in[5];
    const float* W2   = (const float*)d_in[6];
    const float* b2   = (const float*)d_in[7];

    char* ws = (char*)d_ws;
    short* whT   = (short*)(ws);                 // 16,777,216 B
    float* ei    = (float*)(ws + 16777216);      //    524,288 B
    float* ej    = (float*)(ws + 17301504);      //    524,288 B
    float* hp    = (float*)(ws + 17825792);      // 33,554,432 B
    float* sg    = (float*)(ws + 51380224);      //    131,072 B
    float* parts = (float*)(ws + 51511296);      //    524,288 B

    hipLaunchKernelGGL(k1_gemm, dim3(1024), dim3(256), 0, stream, hsrc, W, avec, whT, ei, ej);
    hipLaunchKernelGGL(k2_attn, dim3(2048), dim3(256), 0, stream, Afc, whT, ei, ej, hp);
    hipLaunchKernelGGL(k3_gate, dim3(512), dim3(256), 0, stream, hp, W1, b1, W2, b2, sg);
    hipLaunchKernelGGL(k4a_partial, dim3(512), dim3(256), 0, stream, hp, sg, parts);
    hipLaunchKernelGGL(k4b_reduce, dim3(64), dim3(256), 0, stream, parts, (float*)d_out);
}

// Round 7
// 185.717 us; speedup vs baseline: 1.0127x; 1.0127x over previous
//
#include <hip/hip_runtime.h>

#define BS 64
#define C 512
#define DIN 256
#define DOUT 256
#define H 4
#define HD 64

typedef __attribute__((ext_vector_type(8))) short short8;
typedef __attribute__((ext_vector_type(4))) float f32x4;

__device__ __forceinline__ short f2bf(float f) {
    union { float f; unsigned u; } v; v.f = f;
    unsigned r = v.u + 0x7fffu + ((v.u >> 16) & 1u);
    return (short)(r >> 16);
}

__device__ __forceinline__ short8 pack8(const float* p) {
    short8 r;
#pragma unroll
    for (int i = 0; i < 8; ++i) r[i] = f2bf(p[i]);
    return r;
}

// pack to bf16 AND accumulate the sum of the ROUNDED values (numerator/denominator
// of the softmax share identical rounding -> uniform error cancels)
__device__ __forceinline__ short8 pack8_sum(const float* p, float& s) {
    short8 r;
#pragma unroll
    for (int i = 0; i < 8; ++i) {
        const short b = f2bf(p[i]);
        r[i] = b;
        union { unsigned u; float f; } v;
        v.u = ((unsigned)(unsigned short)b) << 16;
        s += v.f;
    }
    return r;
}

// K1: Wh = h @ W^T (bf16 MFMA), store WhT[b][h][d][c] bf16 + e_i/e_j (pre-scaled
// by log2(e); leaky_relu is positively homogeneous so the scale commutes)
__global__ __launch_bounds__(256) void k1_gemm(
    const float* __restrict__ hsrc, const float* __restrict__ W,
    const float* __restrict__ avec,
    short* __restrict__ whT, float* __restrict__ ei, float* __restrict__ ej)
{
    const int tid = threadIdx.x;
    const int l = tid & 63;
    const int w = tid >> 6;
    const int mtile = blockIdx.x >> 1;
    const int ntile = blockIdx.x & 1;
    const int row_base = mtile * 64 + (w & 1) * 32;     // global row in [0,32768)
    const int col_base = ntile * 128 + (w >> 1) * 64;   // output col in [0,256)
    const int head = col_base >> 6;
    const int lr = l & 15;
    const int kg = (l >> 4) * 8;
    const float L2E = 1.44269504088896f;

    f32x4 acc[2][4];
#pragma unroll
    for (int i = 0; i < 2; ++i)
#pragma unroll
        for (int j = 0; j < 4; ++j) acc[i][j] = f32x4{0.f, 0.f, 0.f, 0.f};

    for (int k0 = 0; k0 < DIN; k0 += 32) {
        short8 af[2];
#pragma unroll
        for (int rt = 0; rt < 2; ++rt) {
            const float* p = hsrc + (size_t)(row_base + rt * 16 + lr) * DIN + k0 + kg;
            float tmp[8];
            *(float4*)(tmp)     = *(const float4*)(p);
            *(float4*)(tmp + 4) = *(const float4*)(p + 4);
            af[rt] = pack8(tmp);
        }
        short8 bfr[4];
#pragma unroll
        for (int ct = 0; ct < 4; ++ct) {
            const float* p = W + (size_t)(col_base + ct * 16 + lr) * DIN + k0 + kg;
            float tmp[8];
            *(float4*)(tmp)     = *(const float4*)(p);
            *(float4*)(tmp + 4) = *(const float4*)(p + 4);
            bfr[ct] = pack8(tmp);
        }
#pragma unroll
        for (int rt = 0; rt < 2; ++rt)
#pragma unroll
            for (int ct = 0; ct < 4; ++ct)
                acc[rt][ct] = __builtin_amdgcn_mfma_f32_16x16x32_bf16(
                    af[rt], bfr[ct], acc[rt][ct], 0, 0, 0);
    }

    float avi[4], avj[4];
#pragma unroll
    for (int ct = 0; ct < 4; ++ct) {
        avi[ct] = avec[head * 2 * HD + ct * 16 + lr];
        avj[ct] = avec[head * 2 * HD + HD + ct * 16 + lr];
    }
#pragma unroll
    for (int rt = 0; rt < 2; ++rt) {
#pragma unroll
        for (int reg = 0; reg < 4; ++reg) {
            const int crow = row_base + rt * 16 + (l >> 4) * 4 + reg;
            const int b = crow >> 9;
            const int c = crow & 511;
            float pi = 0.f, pj = 0.f;
#pragma unroll
            for (int ct = 0; ct < 4; ++ct) {
                const float v = acc[rt][ct][reg];
                pi += v * avi[ct];
                pj += v * avj[ct];
                const int d = ct * 16 + lr;
                whT[((size_t)(b * H + head) * HD + d) * C + c] = f2bf(v);
            }
#pragma unroll
            for (int off = 1; off < 16; off <<= 1) {
                pi += __shfl_xor(pi, off);
                pj += __shfl_xor(pj, off);
            }
            if (lr == 0) {
                ei[(b * H + head) * C + c] = pi * L2E;
                ej[(b * H + head) * C + c] = pj * L2E;
            }
        }
    }
}

// K2: per (b, 16-row i-tile); wave = head; grid 2048, bijective XCD swizzle.
// Software-pipelined: A_fc (HBM-streaming) double-buffered one jt ahead; ej/V
// (XCD-L2-resident) loaded at top of compute phase, covered by exp/pack VALU.
__global__ __launch_bounds__(256) void k2_attn(
    const float* __restrict__ Afc, const short* __restrict__ whT,
    const float* __restrict__ ei, const float* __restrict__ ej,
    float* __restrict__ hp)
{
    const int tid = threadIdx.x;
    const int l = tid & 63;
    const int hh = tid >> 6;
    // nwg=2048, 8 XCDs, 256 blocks/XCD: swz = (bid%8)*256 + bid/8 (bijective);
    // each XCD owns 8 whole b's -> whT/Afc/ej stay XCD-L2-local.
    const int swz = (blockIdx.x & 7) * 256 + (blockIdx.x >> 3);
    const int b = swz >> 5;
    const int i0 = (swz & 31) * 16;
    const int lr = l & 15;
    const int kg = (l >> 4) * 8;

    f32x4 O[4];
#pragma unroll
    for (int dt = 0; dt < 4; ++dt) O[dt] = f32x4{0.f, 0.f, 0.f, 0.f};
    float lsum = 0.f;

    const float eiv = ei[(b * H + hh) * C + i0 + lr];   // already * log2(e)
    const float* ejb = ej + (b * H + hh) * C;           // already * log2(e)
    const short* vb = whT + (size_t)(b * H + hh) * HD * C;
    const float* ap = Afc + ((size_t)b * C + i0 + lr) * C;

    // A prefetch: [0..7] = (j0+kg..+7), [8..15] = (j0+32+kg..+7)
    float Aa[16], Ab[16];

#define LOADA(AV, JT) do {                                             \
        const int _j0 = ((JT) & 7) * 64;                               \
        *(float4*)((AV))      = *(const float4*)(ap + _j0 + kg);       \
        *(float4*)((AV) + 4)  = *(const float4*)(ap + _j0 + kg + 4);   \
        *(float4*)((AV) + 8)  = *(const float4*)(ap + _j0 + 32 + kg);  \
        *(float4*)((AV) + 12) = *(const float4*)(ap + _j0 + 32 + kg + 4);\
    } while (0)

#define COMPUTE(AV, JT) do {                                           \
        const int _j0 = (JT) * 64;                                     \
        float _ejv[16];                                                \
        *(float4*)(_ejv)      = *(const float4*)(ejb + _j0 + kg);      \
        *(float4*)(_ejv + 4)  = *(const float4*)(ejb + _j0 + kg + 4);  \
        *(float4*)(_ejv + 8)  = *(const float4*)(ejb + _j0 + 32 + kg); \
        *(float4*)(_ejv + 12) = *(const float4*)(ejb + _j0 + 32 + kg + 4);\
        short8 _vf[4][2];                                              \
        _Pragma("unroll")                                              \
        for (int dt = 0; dt < 4; ++dt) {                               \
            const short* _vp = vb + (size_t)(dt * 16 + lr) * C + _j0 + kg;\
            _vf[dt][0] = *(const short8*)(_vp);                        \
            _vf[dt][1] = *(const short8*)(_vp + 32);                   \
        }                                                              \
        _Pragma("unroll")                                              \
        for (int t = 0; t < 16; ++t) {                                 \
            const float z = eiv + _ejv[t];                             \
            const float zl = fmaxf(z, 0.2f * z);                       \
            (AV)[t] = exp2f(zl * (AV)[t]);                             \
        }                                                              \
        const short8 _pa0 = pack8_sum((AV), lsum);                     \
        const short8 _pa1 = pack8_sum((AV) + 8, lsum);                 \
        _Pragma("unroll")                                              \
        for (int dt = 0; dt < 4; ++dt) {                               \
            O[dt] = __builtin_amdgcn_mfma_f32_16x16x32_bf16(_pa0, _vf[dt][0], O[dt], 0, 0, 0);\
            O[dt] = __builtin_amdgcn_mfma_f32_16x16x32_bf16(_pa1, _vf[dt][1], O[dt], 0, 0, 0);\
        }                                                              \
    } while (0)

    LOADA(Aa, 0);
#pragma unroll
    for (int jp = 0; jp < 4; ++jp) {
        LOADA(Ab, 2 * jp + 1);
        COMPUTE(Aa, 2 * jp);
        LOADA(Aa, 2 * jp + 2);   // jp=3 -> wraps to jt=0 (harmless warm re-read)
        COMPUTE(Ab, 2 * jp + 1);
    }
#undef LOADA
#undef COMPUTE

    lsum += __shfl_xor(lsum, 16);
    lsum += __shfl_xor(lsum, 32);
    const float inv = 1.0f / lsum;
    float fr[4];
#pragma unroll
    for (int reg = 0; reg < 4; ++reg)
        fr[reg] = __shfl(inv, (l >> 4) * 4 + reg);
#pragma unroll
    for (int dt = 0; dt < 4; ++dt)
#pragma unroll
        for (int reg = 0; reg < 4; ++reg) {
            const int c = i0 + (l >> 4) * 4 + reg;
            hp[((size_t)b * C + c) * DOUT + hh * HD + dt * 16 + lr] =
                O[dt][reg] * fr[reg];
        }
}

// K3: s[c] = tanh(h_prime[c] @ W1^T + b1) @ W2^T + b2 — MFMA GEMM, no LDS.
__global__ __launch_bounds__(256) void k3_gate(
    const float* __restrict__ hp, const float* __restrict__ W1,
    const float* __restrict__ b1, const float* __restrict__ W2,
    const float* __restrict__ b2, float* __restrict__ sgate)
{
    const int t = threadIdx.x;
    const int l = t & 63;
    const int w = t >> 6;
    const int b = blockIdx.x >> 3;
    const int c0 = (blockIdx.x & 7) * 64;
    const int lr = l & 15;
    const int kg = (l >> 4) * 8;

    f32x4 acc[4];
#pragma unroll
    for (int ct = 0; ct < 4; ++ct) acc[ct] = f32x4{0.f, 0.f, 0.f, 0.f};

    const float* arow = hp + (size_t)(b * C + c0 + w * 16 + lr) * DOUT;
    for (int k0 = 0; k0 < DOUT; k0 += 32) {
        float ta[8];
        *(float4*)(ta)     = *(const float4*)(arow + k0 + kg);
        *(float4*)(ta + 4) = *(const float4*)(arow + k0 + kg + 4);
        const short8 af = pack8(ta);
#pragma unroll
        for (int ct = 0; ct < 4; ++ct) {
            const float* bp = W1 + (size_t)(ct * 16 + lr) * DOUT + k0 + kg;
            float tb[8];
            *(float4*)(tb)     = *(const float4*)(bp);
            *(float4*)(tb + 4) = *(const float4*)(bp + 4);
            acc[ct] = __builtin_amdgcn_mfma_f32_16x16x32_bf16(af, pack8(tb), acc[ct], 0, 0, 0);
        }
    }

    float b1v[4], w2v[4];
#pragma unroll
    for (int ct = 0; ct < 4; ++ct) {
        b1v[ct] = b1[ct * 16 + lr];
        w2v[ct] = W2[ct * 16 + lr];
    }
    const float b2v = b2[0];
#pragma unroll
    for (int reg = 0; reg < 4; ++reg) {
        float val = 0.f;
#pragma unroll
        for (int ct = 0; ct < 4; ++ct)
            val += tanhf(acc[ct][reg] + b1v[ct]) * w2v[ct];
#pragma unroll
        for (int off = 1; off < 16; off <<= 1) val += __shfl_xor(val, off);
        if (lr == 0)
            sgate[b * C + c0 + w * 16 + (l >> 4) * 4 + reg] = val + b2v;
    }
}

// K4a: per (b, 64-channel chunk): redundant block softmax over sgate + weighted
// partial sum of hp rows (coalesced). 512 blocks.
__global__ __launch_bounds__(256) void k4a_partial(
    const float* __restrict__ hp, const float* __restrict__ sgate,
    float* __restrict__ partial)
{
    __shared__ float red[16];
    __shared__ float wlds[64];
    const int t = threadIdx.x;
    const int b = blockIdx.x >> 3;
    const int c0 = (blockIdx.x & 7) * 64;
    const int l = t & 63, w = t >> 6;
    const float L2E = 1.44269504088896f;

    const float s0 = sgate[b * C + t], s1 = sgate[b * C + 256 + t];
    float mx = fmaxf(s0, s1);
#pragma unroll
    for (int off = 1; off < 64; off <<= 1) mx = fmaxf(mx, __shfl_xor(mx, off));
    if (l == 0) red[w] = mx;
    __syncthreads();
    mx = fmaxf(fmaxf(red[0], red[1]), fmaxf(red[2], red[3]));
    float sum = exp2f((s0 - mx) * L2E) + exp2f((s1 - mx) * L2E);
#pragma unroll
    for (int off = 1; off < 64; off <<= 1) sum += __shfl_xor(sum, off);
    if (l == 0) red[8 + w] = sum;
    __syncthreads();
    sum = red[8] + red[9] + red[10] + red[11];
    const float inv = 1.f / sum;
    if (t < 64)
        wlds[t] = exp2f((sgate[b * C + c0 + t] - mx) * L2E) * inv;
    __syncthreads();

    float acc = 0.f;
    const float* base = hp + ((size_t)b * C + c0) * DOUT + t;
#pragma unroll 4
    for (int c = 0; c < 64; ++c) acc += wlds[c] * base[(size_t)c * DOUT];
    partial[(size_t)blockIdx.x * DOUT + t] = acc;
}

// K4b: reduce the 8 chunk-partials per batch -> f32 out
__global__ __launch_bounds__(256) void k4b_reduce(
    const float* __restrict__ partial, float* __restrict__ out)
{
    const int t = threadIdx.x;
    const int b = blockIdx.x;
    float s = 0.f;
#pragma unroll
    for (int k = 0; k < 8; ++k)
        s += partial[(size_t)(b * 8 + k) * DOUT + t];
    out[b * DOUT + t] = s;
}

extern "C" void kernel_launch(void* const* d_in, const int* in_sizes, int n_in,
                              void* d_out, int out_size, void* d_ws, size_t ws_size,
                              hipStream_t stream) {
    const float* hsrc = (const float*)d_in[0];
    const float* Afc  = (const float*)d_in[1];
    const float* W    = (const float*)d_in[2];
    const float* avec = (const float*)d_in[3];
    const float* W1   = (const float*)d_in[4];
    const float* b1   = (const float*)d_in[5];
    const float* W2   = (const float*)d_in[6];
    const float* b2   = (const float*)d_in[7];

    char* ws = (char*)d_ws;
    short* whT   = (short*)(ws);                 // 16,777,216 B
    float* ei    = (float*)(ws + 16777216);      //    524,288 B
    float* ej    = (float*)(ws + 17301504);      //    524,288 B
    float* hp    = (float*)(ws + 17825792);      // 33,554,432 B
    float* sg    = (float*)(ws + 51380224);      //    131,072 B
    float* parts = (float*)(ws + 51511296);      //    524,288 B

    hipLaunchKernelGGL(k1_gemm, dim3(1024), dim3(256), 0, stream, hsrc, W, avec, whT, ei, ej);
    hipLaunchKernelGGL(k2_attn, dim3(2048), dim3(256), 0, stream, Afc, whT, ei, ej, hp);
    hipLaunchKernelGGL(k3_gate, dim3(512), dim3(256), 0, stream, hp, W1, b1, W2, b2, sg);
    hipLaunchKernelGGL(k4a_partial, dim3(512), dim3(256), 0, stream, hp, sg, parts);
    hipLaunchKernelGGL(k4b_reduce, dim3(64), dim3(256), 0, stream, parts, (float*)d_out);
}

// Round 8
// 121.010 us; speedup vs baseline: 1.5542x; 1.5347x over previous
//
#include <hip/hip_runtime.h>

#define BS 64
#define C 512
#define DIN 256
#define DOUT 256
#define H 4
#define HD 64

typedef __attribute__((ext_vector_type(8))) short short8;
typedef __attribute__((ext_vector_type(4))) short short4v;
typedef __attribute__((ext_vector_type(4))) float f32x4;

__device__ __forceinline__ short f2bf(float f) {
    union { float f; unsigned u; } v; v.f = f;
    unsigned r = v.u + 0x7fffu + ((v.u >> 16) & 1u);
    return (short)(r >> 16);
}

__device__ __forceinline__ short8 pack8(const float* p) {
    short8 r;
#pragma unroll
    for (int i = 0; i < 8; ++i) r[i] = f2bf(p[i]);
    return r;
}

// pack to bf16 AND accumulate the sum of the ROUNDED values (numerator/denominator
// of the softmax share identical rounding -> uniform error cancels)
__device__ __forceinline__ short8 pack8_sum(const float* p, float& s) {
    short8 r;
#pragma unroll
    for (int i = 0; i < 8; ++i) {
        const short b = f2bf(p[i]);
        r[i] = b;
        union { unsigned u; float f; } v;
        v.u = ((unsigned)(unsigned short)b) << 16;
        s += v.f;
    }
    return r;
}

// K1: Wh = h @ W^T (bf16 MFMA). whT stored in MFMA-B-FRAGMENT order:
// per (b,h): unit(jt,dt) of 1024 shorts; element (j,d) at
//   (jt*4+dt)*1024 + ((j&63)>>5)*512 + ((d&15) + 16*((j&31)>>3))*8 + (j&7)
// so K2's V loads are contiguous 1KB per wave-instruction.
// ei/ej pre-scaled by log2(e) (leaky_relu is positively homogeneous).
__global__ __launch_bounds__(256) void k1_gemm(
    const float* __restrict__ hsrc, const float* __restrict__ W,
    const float* __restrict__ avec,
    short* __restrict__ whT, float* __restrict__ ei, float* __restrict__ ej)
{
    const int tid = threadIdx.x;
    const int l = tid & 63;
    const int w = tid >> 6;
    const int mtile = blockIdx.x >> 1;
    const int ntile = blockIdx.x & 1;
    const int row_base = mtile * 64 + (w & 1) * 32;     // global row in [0,32768)
    const int col_base = ntile * 128 + (w >> 1) * 64;   // output col in [0,256)
    const int head = col_base >> 6;
    const int lr = l & 15;
    const int kg = (l >> 4) * 8;
    const float L2E = 1.44269504088896f;

    f32x4 acc[2][4];
#pragma unroll
    for (int i = 0; i < 2; ++i)
#pragma unroll
        for (int j = 0; j < 4; ++j) acc[i][j] = f32x4{0.f, 0.f, 0.f, 0.f};

    for (int k0 = 0; k0 < DIN; k0 += 32) {
        short8 af[2];
#pragma unroll
        for (int rt = 0; rt < 2; ++rt) {
            const float* p = hsrc + (size_t)(row_base + rt * 16 + lr) * DIN + k0 + kg;
            float tmp[8];
            *(float4*)(tmp)     = *(const float4*)(p);
            *(float4*)(tmp + 4) = *(const float4*)(p + 4);
            af[rt] = pack8(tmp);
        }
        short8 bfr[4];
#pragma unroll
        for (int ct = 0; ct < 4; ++ct) {
            const float* p = W + (size_t)(col_base + ct * 16 + lr) * DIN + k0 + kg;
            float tmp[8];
            *(float4*)(tmp)     = *(const float4*)(p);
            *(float4*)(tmp + 4) = *(const float4*)(p + 4);
            bfr[ct] = pack8(tmp);
        }
#pragma unroll
        for (int rt = 0; rt < 2; ++rt)
#pragma unroll
            for (int ct = 0; ct < 4; ++ct)
                acc[rt][ct] = __builtin_amdgcn_mfma_f32_16x16x32_bf16(
                    af[rt], bfr[ct], acc[rt][ct], 0, 0, 0);
    }

    float avi[4], avj[4];
#pragma unroll
    for (int ct = 0; ct < 4; ++ct) {
        avi[ct] = avec[head * 2 * HD + ct * 16 + lr];
        avj[ct] = avec[head * 2 * HD + HD + ct * 16 + lr];
    }

    const int q0 = (l >> 4) * 4;       // 0,4,8,12
    const int t0 = q0 & 7;             // 0,4
    const int g0 = q0 >> 3;            // 0,1
    const int jt = mtile & 7;
    const int bb = mtile >> 3;
    const int half = w & 1;
    short* fragb = whT + (size_t)(bb * H + head) * (HD * C);

#pragma unroll
    for (int rt = 0; rt < 2; ++rt) {
        const int lane2 = lr + 16 * (rt * 2 + g0);
#pragma unroll
        for (int ct = 0; ct < 4; ++ct) {
            short4v sv;
#pragma unroll
            for (int reg = 0; reg < 4; ++reg) sv[reg] = f2bf(acc[rt][ct][reg]);
            *(short4v*)(fragb + (jt * 4 + ct) * 1024 + half * 512 + lane2 * 8 + t0) = sv;
        }
#pragma unroll
        for (int reg = 0; reg < 4; ++reg) {
            const int crow = row_base + rt * 16 + q0 + reg;
            const int b = crow >> 9;
            const int c = crow & 511;
            float pi = 0.f, pj = 0.f;
#pragma unroll
            for (int ct = 0; ct < 4; ++ct) {
                pi += acc[rt][ct][reg] * avi[ct];
                pj += acc[rt][ct][reg] * avj[ct];
            }
#pragma unroll
            for (int off = 1; off < 16; off <<= 1) {
                pi += __shfl_xor(pi, off);
                pj += __shfl_xor(pj, off);
            }
            if (lr == 0) {
                ei[(b * H + head) * C + c] = pi * L2E;
                ej[(b * H + head) * C + c] = pj * L2E;
            }
        }
    }
}

// K2: per (b, 16-row i-tile); wave = head; grid 2048, bijective XCD swizzle.
// A_fc staged once in LDS (coalesced 32KB linear copy; [16][516] pad ->
// uniform-bank ds_read_b128). V read in fragment order (contiguous 1KB/inst).
__global__ __launch_bounds__(256) void k2_attn(
    const float* __restrict__ Afc, const short* __restrict__ whT,
    const float* __restrict__ ei, const float* __restrict__ ej,
    float* __restrict__ hp)
{
    __shared__ float alds[16 * 516];
    const int tid = threadIdx.x;
    const int l = tid & 63;
    const int hh = tid >> 6;
    // nwg=2048, 8 XCDs: swz = (bid%8)*256 + bid/8 (bijective); each XCD owns
    // 8 whole b's -> whT/ej stay XCD-L2-local.
    const int swz = (blockIdx.x & 7) * 256 + (blockIdx.x >> 3);
    const int b = swz >> 5;
    const int i0 = (swz & 31) * 16;
    const int lr = l & 15;
    const int kg = (l >> 4) * 8;

    // stage A rows [i0, i0+16) x [0,512): 32KB, linear in global -> coalesced
    {
        const float* asrc = Afc + ((size_t)b * C + i0) * C;
#pragma unroll
        for (int k = 0; k < 8; ++k) {
            const int idx = tid + k * 256;           // float4 index, 2048 total
            const int row = idx >> 7;
            const int col = (idx & 127) * 4;
            *(float4*)(&alds[row * 516 + col]) = *(const float4*)(asrc + (size_t)idx * 4);
        }
    }
    __syncthreads();

    f32x4 O[4];
#pragma unroll
    for (int dt = 0; dt < 4; ++dt) O[dt] = f32x4{0.f, 0.f, 0.f, 0.f};
    float lsum = 0.f;

    const float eiv = ei[(b * H + hh) * C + i0 + lr];   // already * log2(e)
    const float* ejb = ej + (b * H + hh) * C;           // already * log2(e)
    const short* vb = whT + (size_t)(b * H + hh) * (HD * C);
    const float* arow = &alds[lr * 516];

    for (int jt = 0; jt < 8; ++jt) {
        const int j0 = jt * 64;

        short8 vf[4][2];
#pragma unroll
        for (int dt = 0; dt < 4; ++dt) {
            const short* vp = vb + (jt * 4 + dt) * 1024 + l * 8;
            vf[dt][0] = *(const short8*)(vp);
            vf[dt][1] = *(const short8*)(vp + 512);
        }

        float ejv[16];
        *(float4*)(ejv)      = *(const float4*)(ejb + j0 + kg);
        *(float4*)(ejv + 4)  = *(const float4*)(ejb + j0 + kg + 4);
        *(float4*)(ejv + 8)  = *(const float4*)(ejb + j0 + 32 + kg);
        *(float4*)(ejv + 12) = *(const float4*)(ejb + j0 + 32 + kg + 4);

        float av[16];
        *(float4*)(av)      = *(const float4*)(arow + j0 + kg);
        *(float4*)(av + 4)  = *(const float4*)(arow + j0 + kg + 4);
        *(float4*)(av + 8)  = *(const float4*)(arow + j0 + 32 + kg);
        *(float4*)(av + 12) = *(const float4*)(arow + j0 + 32 + kg + 4);

#pragma unroll
        for (int t = 0; t < 16; ++t) {
            const float z = eiv + ejv[t];
            const float zl = fmaxf(z, 0.2f * z);
            av[t] = exp2f(zl * av[t]);
        }

        const short8 pa0 = pack8_sum(av, lsum);
        const short8 pa1 = pack8_sum(av + 8, lsum);
#pragma unroll
        for (int dt = 0; dt < 4; ++dt) {
            O[dt] = __builtin_amdgcn_mfma_f32_16x16x32_bf16(pa0, vf[dt][0], O[dt], 0, 0, 0);
            O[dt] = __builtin_amdgcn_mfma_f32_16x16x32_bf16(pa1, vf[dt][1], O[dt], 0, 0, 0);
        }
    }

    lsum += __shfl_xor(lsum, 16);
    lsum += __shfl_xor(lsum, 32);
    const float inv = 1.0f / lsum;
    float fr[4];
#pragma unroll
    for (int reg = 0; reg < 4; ++reg)
        fr[reg] = __shfl(inv, (l >> 4) * 4 + reg);
#pragma unroll
    for (int dt = 0; dt < 4; ++dt)
#pragma unroll
        for (int reg = 0; reg < 4; ++reg) {
            const int c = i0 + (l >> 4) * 4 + reg;
            hp[((size_t)b * C + c) * DOUT + hh * HD + dt * 16 + lr] =
                O[dt][reg] * fr[reg];
        }
}

// K3: s[c] = tanh(h_prime[c] @ W1^T + b1) @ W2^T + b2 — MFMA GEMM, no LDS.
__global__ __launch_bounds__(256) void k3_gate(
    const float* __restrict__ hp, const float* __restrict__ W1,
    const float* __restrict__ b1, const float* __restrict__ W2,
    const float* __restrict__ b2, float* __restrict__ sgate)
{
    const int t = threadIdx.x;
    const int l = t & 63;
    const int w = t >> 6;
    const int b = blockIdx.x >> 3;
    const int c0 = (blockIdx.x & 7) * 64;
    const int lr = l & 15;
    const int kg = (l >> 4) * 8;

    f32x4 acc[4];
#pragma unroll
    for (int ct = 0; ct < 4; ++ct) acc[ct] = f32x4{0.f, 0.f, 0.f, 0.f};

    const float* arow = hp + (size_t)(b * C + c0 + w * 16 + lr) * DOUT;
    for (int k0 = 0; k0 < DOUT; k0 += 32) {
        float ta[8];
        *(float4*)(ta)     = *(const float4*)(arow + k0 + kg);
        *(float4*)(ta + 4) = *(const float4*)(arow + k0 + kg + 4);
        const short8 af = pack8(ta);
#pragma unroll
        for (int ct = 0; ct < 4; ++ct) {
            const float* bp = W1 + (size_t)(ct * 16 + lr) * DOUT + k0 + kg;
            float tb[8];
            *(float4*)(tb)     = *(const float4*)(bp);
            *(float4*)(tb + 4) = *(const float4*)(bp + 4);
            acc[ct] = __builtin_amdgcn_mfma_f32_16x16x32_bf16(af, pack8(tb), acc[ct], 0, 0, 0);
        }
    }

    float b1v[4], w2v[4];
#pragma unroll
    for (int ct = 0; ct < 4; ++ct) {
        b1v[ct] = b1[ct * 16 + lr];
        w2v[ct] = W2[ct * 16 + lr];
    }
    const float b2v = b2[0];
#pragma unroll
    for (int reg = 0; reg < 4; ++reg) {
        float val = 0.f;
#pragma unroll
        for (int ct = 0; ct < 4; ++ct)
            val += tanhf(acc[ct][reg] + b1v[ct]) * w2v[ct];
#pragma unroll
        for (int off = 1; off < 16; off <<= 1) val += __shfl_xor(val, off);
        if (lr == 0)
            sgate[b * C + c0 + w * 16 + (l >> 4) * 4 + reg] = val + b2v;
    }
}

// K4a: per (b, 64-channel chunk): redundant block softmax over sgate + weighted
// partial sum of hp rows (coalesced). 512 blocks.
__global__ __launch_bounds__(256) void k4a_partial(
    const float* __restrict__ hp, const float* __restrict__ sgate,
    float* __restrict__ partial)
{
    __shared__ float red[16];
    __shared__ float wlds[64];
    const int t = threadIdx.x;
    const int b = blockIdx.x >> 3;
    const int c0 = (blockIdx.x & 7) * 64;
    const int l = t & 63, w = t >> 6;
    const float L2E = 1.44269504088896f;

    const float s0 = sgate[b * C + t], s1 = sgate[b * C + 256 + t];
    float mx = fmaxf(s0, s1);
#pragma unroll
    for (int off = 1; off < 64; off <<= 1) mx = fmaxf(mx, __shfl_xor(mx, off));
    if (l == 0) red[w] = mx;
    __syncthreads();
    mx = fmaxf(fmaxf(red[0], red[1]), fmaxf(red[2], red[3]));
    float sum = exp2f((s0 - mx) * L2E) + exp2f((s1 - mx) * L2E);
#pragma unroll
    for (int off = 1; off < 64; off <<= 1) sum += __shfl_xor(sum, off);
    if (l == 0) red[8 + w] = sum;
    __syncthreads();
    sum = red[8] + red[9] + red[10] + red[11];
    const float inv = 1.f / sum;
    if (t < 64)
        wlds[t] = exp2f((sgate[b * C + c0 + t] - mx) * L2E) * inv;
    __syncthreads();

    float acc = 0.f;
    const float* base = hp + ((size_t)b * C + c0) * DOUT + t;
#pragma unroll 4
    for (int c = 0; c < 64; ++c) acc += wlds[c] * base[(size_t)c * DOUT];
    partial[(size_t)blockIdx.x * DOUT + t] = acc;
}

// K4b: reduce the 8 chunk-partials per batch -> f32 out
__global__ __launch_bounds__(256) void k4b_reduce(
    const float* __restrict__ partial, float* __restrict__ out)
{
    const int t = threadIdx.x;
    const int b = blockIdx.x;
    float s = 0.f;
#pragma unroll
    for (int k = 0; k < 8; ++k)
        s += partial[(size_t)(b * 8 + k) * DOUT + t];
    out[b * DOUT + t] = s;
}

extern "C" void kernel_launch(void* const* d_in, const int* in_sizes, int n_in,
                              void* d_out, int out_size, void* d_ws, size_t ws_size,
                              hipStream_t stream) {
    const float* hsrc = (const float*)d_in[0];
    const float* Afc  = (const float*)d_in[1];
    const float* W    = (const float*)d_in[2];
    const float* avec = (const float*)d_in[3];
    const float* W1   = (const float*)d_in[4];
    const float* b1   = (const float*)d_in[5];
    const float* W2   = (const float*)d_in[6];
    const float* b2   = (const float*)d_in[7];

    char* ws = (char*)d_ws;
    short* whT   = (short*)(ws);                 // 16,777,216 B (fragment order)
    float* ei    = (float*)(ws + 16777216);      //    524,288 B
    float* ej    = (float*)(ws + 17301504);      //    524,288 B
    float* hp    = (float*)(ws + 17825792);      // 33,554,432 B
    float* sg    = (float*)(ws + 51380224);      //    131,072 B
    float* parts = (float*)(ws + 51511296);      //    524,288 B

    hipLaunchKernelGGL(k1_gemm, dim3(1024), dim3(256), 0, stream, hsrc, W, avec, whT, ei, ej);
    hipLaunchKernelGGL(k2_attn, dim3(2048), dim3(256), 0, stream, Afc, whT, ei, ej, hp);
    hipLaunchKernelGGL(k3_gate, dim3(512), dim3(256), 0, stream, hp, W1, b1, W2, b2, sg);
    hipLaunchKernelGGL(k4a_partial, dim3(512), dim3(256), 0, stream, hp, sg, parts);
    hipLaunchKernelGGL(k4b_reduce, dim3(64), dim3(256), 0, stream, parts, (float*)d_out);
}

// Round 9
// 81.932 us; speedup vs baseline: 2.2955x; 1.4770x over previous
//
#include <hip/hip_runtime.h>
#include <hip/hip_bf16.h>

#define BS 64
#define C 512
#define DIN 256
#define DOUT 256
#define H 4
#define HD 64

typedef __attribute__((ext_vector_type(8))) short short8;
typedef __attribute__((ext_vector_type(4))) short short4v;
typedef __attribute__((ext_vector_type(4))) float f32x4;

// native RNE f32->bf16 (compiler pairs into v_cvt_pk_bf16_f32; m240: do NOT hand-write asm)
__device__ __forceinline__ short bfc(float f) {
    union { __hip_bfloat16 h; unsigned short s; } u;
    u.h = __float2bfloat16(f);
    return (short)u.s;
}

__device__ __forceinline__ float bf2f(short v) {
    union { unsigned u; float f; } x;
    x.u = ((unsigned)(unsigned short)v) << 16;
    return x.f;
}

__device__ __forceinline__ short8 pack8n(const float* p) {
    short8 r;
#pragma unroll
    for (int i = 0; i < 8; ++i) r[i] = bfc(p[i]);
    return r;
}

// K0: one-time W/W1 -> bf16 (so GEMM B-fragments are dense 64B-line reads, no per-use cvt)
__global__ __launch_bounds__(256) void k0_prep(
    const float* __restrict__ W, const float* __restrict__ W1,
    short* __restrict__ Wbf, short* __restrict__ W1bf)
{
    const int idx = blockIdx.x * 256 + threadIdx.x;   // short8 slot
    if (idx < 8192) {                                  // W: 256*256
        float t[8];
        *(float4*)(t)     = *(const float4*)(W + idx * 8);
        *(float4*)(t + 4) = *(const float4*)(W + idx * 8 + 4);
        *(short8*)(Wbf + idx * 8) = pack8n(t);
    } else if (idx < 10240) {                          // W1: 64*256
        const int j = idx - 8192;
        float t[8];
        *(float4*)(t)     = *(const float4*)(W1 + j * 8);
        *(float4*)(t + 4) = *(const float4*)(W1 + j * 8 + 4);
        *(short8*)(W1bf + j * 8) = pack8n(t);
    }
}

// K1: Wh = h @ W^T. Block = 64 rows x 256 cols (wave = head). h tile staged
// coalesced -> bf16 -> XOR-swizzled LDS; W fragments from Wbf (dense lines).
// whT written in MFMA-B-fragment order (same layout K2 consumes); ei/ej *log2e.
__global__ __launch_bounds__(256) void k1_gemm(
    const float* __restrict__ hsrc, const short* __restrict__ Wbf,
    const float* __restrict__ avec,
    short* __restrict__ whT, float* __restrict__ ei, float* __restrict__ ej)
{
    __shared__ __align__(16) short hs[64 * 256];      // 32KB bf16
    const int tid = threadIdx.x;
    const int l = tid & 63;
    const int w = tid >> 6;
    const int lr = l & 15;
    const int g = l >> 4;
    const int kg = g * 8;
    const int mtile = blockIdx.x;                     // 512 blocks
    const int row0 = mtile * 64;
    const float L2E = 1.44269504088896f;

    // stage h rows [row0, row0+64) x [0,256): 64KB f32 coalesced -> 32KB bf16 LDS
#pragma unroll
    for (int it = 0; it < 8; ++it) {
        const int idx = tid + it * 256;               // 2048 slots: 64 rows x 32 col-groups
        const int row = idx >> 5;
        const int colg = idx & 31;
        const float* p = hsrc + (size_t)(row0 + row) * DIN + colg * 8;
        float t[8];
        *(float4*)(t)     = *(const float4*)(p);
        *(float4*)(t + 4) = *(const float4*)(p + 4);
        const int off = (row * 512 + colg * 16) ^ ((row & 7) << 4);
        *(short8*)((char*)hs + off) = pack8n(t);
    }
    __syncthreads();

    const int head = w;
    f32x4 acc[4][4];
#pragma unroll
    for (int i = 0; i < 4; ++i)
#pragma unroll
        for (int j = 0; j < 4; ++j) acc[i][j] = f32x4{0.f, 0.f, 0.f, 0.f};

    for (int k0 = 0; k0 < DIN; k0 += 32) {
        short8 af[4];
#pragma unroll
        for (int rt = 0; rt < 4; ++rt) {
            const int row = rt * 16 + lr;
            const int off = (row * 512 + (k0 + kg) * 2) ^ ((row & 7) << 4);
            af[rt] = *(const short8*)((const char*)hs + off);
        }
        short8 bfr[4];
#pragma unroll
        for (int ct = 0; ct < 4; ++ct)
            bfr[ct] = *(const short8*)(Wbf + (size_t)(head * 64 + ct * 16 + lr) * DIN + k0 + kg);
#pragma unroll
        for (int rt = 0; rt < 4; ++rt)
#pragma unroll
            for (int ct = 0; ct < 4; ++ct)
                acc[rt][ct] = __builtin_amdgcn_mfma_f32_16x16x32_bf16(
                    af[rt], bfr[ct], acc[rt][ct], 0, 0, 0);
    }

    float avi[4], avj[4];
#pragma unroll
    for (int ct = 0; ct < 4; ++ct) {
        avi[ct] = avec[head * 2 * HD + ct * 16 + lr];
        avj[ct] = avec[head * 2 * HD + HD + ct * 16 + lr];
    }

    const int jt = mtile & 7;
    const int bb = mtile >> 3;
    short* fragb = whT + (size_t)(bb * H + head) * (HD * C);

#pragma unroll
    for (int rt = 0; rt < 4; ++rt) {
        const int lane2 = lr + 16 * ((rt & 1) * 2 + (g >> 1));
        const int t0 = (g & 1) * 4;
        const int half = rt >> 1;
#pragma unroll
        for (int ct = 0; ct < 4; ++ct) {
            short4v sv;
#pragma unroll
            for (int reg = 0; reg < 4; ++reg) sv[reg] = bfc(acc[rt][ct][reg]);
            *(short4v*)(fragb + (jt * 4 + ct) * 1024 + half * 512 + lane2 * 8 + t0) = sv;
        }
#pragma unroll
        for (int reg = 0; reg < 4; ++reg) {
            const int j = row0 + rt * 16 + g * 4 + reg;
            const int b = j >> 9;
            const int c = j & 511;
            float pi = 0.f, pj = 0.f;
#pragma unroll
            for (int ct = 0; ct < 4; ++ct) {
                pi += acc[rt][ct][reg] * avi[ct];
                pj += acc[rt][ct][reg] * avj[ct];
            }
#pragma unroll
            for (int off = 1; off < 16; off <<= 1) {
                pi += __shfl_xor(pi, off);
                pj += __shfl_xor(pj, off);
            }
            if (lr == 0) {
                ei[(b * H + head) * C + c] = pi * L2E;
                ej[(b * H + head) * C + c] = pj * L2E;
            }
        }
    }
}

// K2: per (b, 16-row i-tile); wave = head; grid 2048, bijective XCD swizzle.
// A_fc staged in XOR-swizzled LDS (32KB -> 5 blocks/CU); V in fragment order;
// native cvt_pk packing; raw-f32 lsum; hp stored bf16.
__global__ __launch_bounds__(256) void k2_attn(
    const float* __restrict__ Afc, const short* __restrict__ whT,
    const float* __restrict__ ei, const float* __restrict__ ej,
    short* __restrict__ hpb)
{
    __shared__ __align__(16) float alds[16 * 512];    // 32KB
    const int tid = threadIdx.x;
    const int l = tid & 63;
    const int hh = tid >> 6;
    const int swz = (blockIdx.x & 7) * 256 + (blockIdx.x >> 3);  // bijective, 2048%8==0
    const int b = swz >> 5;
    const int i0 = (swz & 31) * 16;
    const int lr = l & 15;
    const int kg = (l >> 4) * 8;

    // stage A rows [i0,i0+16) x [0,512): coalesced, XOR-swizzled
    {
        const float* asrc = Afc + ((size_t)b * C + i0) * C;
#pragma unroll
        for (int k = 0; k < 8; ++k) {
            const int idx = tid + k * 256;            // float4 slots
            const int row = idx >> 7;
            const int off = (idx * 16) ^ ((row & 7) << 4);
            *(float4*)((char*)alds + off) = *(const float4*)(asrc + (size_t)idx * 4);
        }
    }
    __syncthreads();

    f32x4 O[4];
#pragma unroll
    for (int dt = 0; dt < 4; ++dt) O[dt] = f32x4{0.f, 0.f, 0.f, 0.f};
    float lsum = 0.f;

    const float eiv = ei[(b * H + hh) * C + i0 + lr];    // already * log2(e)
    const float* ejb = ej + (b * H + hh) * C;            // already * log2(e)
    const short* vb = whT + (size_t)(b * H + hh) * (HD * C);
    const int abase = lr * 2048;                          // byte base of this lane's A row
    const int aswz = (lr & 7) << 4;

    for (int jt = 0; jt < 8; ++jt) {
        const int j0 = jt * 64;

        short8 vf[4][2];
#pragma unroll
        for (int dt = 0; dt < 4; ++dt) {
            const short* vp = vb + (jt * 4 + dt) * 1024 + l * 8;
            vf[dt][0] = *(const short8*)(vp);
            vf[dt][1] = *(const short8*)(vp + 512);
        }

        float ejv[16];
        *(float4*)(ejv)      = *(const float4*)(ejb + j0 + kg);
        *(float4*)(ejv + 4)  = *(const float4*)(ejb + j0 + kg + 4);
        *(float4*)(ejv + 8)  = *(const float4*)(ejb + j0 + 32 + kg);
        *(float4*)(ejv + 12) = *(const float4*)(ejb + j0 + 32 + kg + 4);

        float av[16];
        *(float4*)(av)      = *(const float4*)((const char*)alds + ((abase + (j0 + kg) * 4) ^ aswz));
        *(float4*)(av + 4)  = *(const float4*)((const char*)alds + ((abase + (j0 + kg) * 4 + 16) ^ aswz));
        *(float4*)(av + 8)  = *(const float4*)((const char*)alds + ((abase + (j0 + 32 + kg) * 4) ^ aswz));
        *(float4*)(av + 12) = *(const float4*)((const char*)alds + ((abase + (j0 + 32 + kg) * 4 + 16) ^ aswz));

#pragma unroll
        for (int t = 0; t < 16; ++t) {
            const float z = eiv + ejv[t];
            const float zl = fmaxf(z, 0.2f * z);
            const float e = exp2f(zl * av[t]);
            av[t] = e;
            lsum += e;
        }

        const short8 pa0 = pack8n(av);
        const short8 pa1 = pack8n(av + 8);
#pragma unroll
        for (int dt = 0; dt < 4; ++dt) {
            O[dt] = __builtin_amdgcn_mfma_f32_16x16x32_bf16(pa0, vf[dt][0], O[dt], 0, 0, 0);
            O[dt] = __builtin_amdgcn_mfma_f32_16x16x32_bf16(pa1, vf[dt][1], O[dt], 0, 0, 0);
        }
    }

    lsum += __shfl_xor(lsum, 16);
    lsum += __shfl_xor(lsum, 32);
    const float inv = 1.0f / lsum;
    float fr[4];
#pragma unroll
    for (int reg = 0; reg < 4; ++reg)
        fr[reg] = __shfl(inv, (l >> 4) * 4 + reg);
#pragma unroll
    for (int dt = 0; dt < 4; ++dt)
#pragma unroll
        for (int reg = 0; reg < 4; ++reg) {
            const int c = i0 + (l >> 4) * 4 + reg;
            hpb[((size_t)b * C + c) * DOUT + hh * HD + dt * 16 + lr] =
                bfc(O[dt][reg] * fr[reg]);
        }
}

// K3: s = tanh(hp @ W1^T + b1) @ W2^T + b2. hp tile (bf16) staged into
// XOR-swizzled LDS by straight short8 copy; W1 fragments from W1bf.
__global__ __launch_bounds__(256) void k3_gate(
    const short* __restrict__ hpb, const short* __restrict__ W1bf,
    const float* __restrict__ b1, const float* __restrict__ W2,
    const float* __restrict__ b2, float* __restrict__ sgate)
{
    __shared__ __align__(16) short hs[64 * 256];      // 32KB
    const int t = threadIdx.x;
    const int l = t & 63;
    const int w = t >> 6;
    const int b = blockIdx.x >> 3;
    const int c0 = (blockIdx.x & 7) * 64;
    const int lr = l & 15;
    const int kg = (l >> 4) * 8;

    {
        const short* src = hpb + ((size_t)b * C + c0) * DOUT;
#pragma unroll
        for (int it = 0; it < 8; ++it) {
            const int idx = t + it * 256;             // 2048 slots: 64 rows x 32 groups
            const int row = idx >> 5;
            const int colg = idx & 31;
            const int off = (row * 512 + colg * 16) ^ ((row & 7) << 4);
            *(short8*)((char*)hs + off) = *(const short8*)(src + row * 256 + colg * 8);
        }
    }
    __syncthreads();

    f32x4 acc[4];
#pragma unroll
    for (int ct = 0; ct < 4; ++ct) acc[ct] = f32x4{0.f, 0.f, 0.f, 0.f};

    const int myrow = w * 16 + lr;
    for (int k0 = 0; k0 < DOUT; k0 += 32) {
        const int off = (myrow * 512 + (k0 + kg) * 2) ^ ((myrow & 7) << 4);
        const short8 af = *(const short8*)((const char*)hs + off);
#pragma unroll
        for (int ct = 0; ct < 4; ++ct) {
            const short8 bfr = *(const short8*)(W1bf + (size_t)(ct * 16 + lr) * DOUT + k0 + kg);
            acc[ct] = __builtin_amdgcn_mfma_f32_16x16x32_bf16(af, bfr, acc[ct], 0, 0, 0);
        }
    }

    float b1v[4], w2v[4];
#pragma unroll
    for (int ct = 0; ct < 4; ++ct) {
        b1v[ct] = b1[ct * 16 + lr];
        w2v[ct] = W2[ct * 16 + lr];
    }
    const float b2v = b2[0];
#pragma unroll
    for (int reg = 0; reg < 4; ++reg) {
        float val = 0.f;
#pragma unroll
        for (int ct = 0; ct < 4; ++ct)
            val += tanhf(acc[ct][reg] + b1v[ct]) * w2v[ct];
#pragma unroll
        for (int off = 1; off < 16; off <<= 1) val += __shfl_xor(val, off);
        if (lr == 0)
            sgate[b * C + c0 + w * 16 + (l >> 4) * 4 + reg] = val + b2v;
    }
}

// K4a: per (b, 64-channel chunk): redundant softmax over sgate + weighted
// partial sum of bf16 hp rows (coalesced). 512 blocks.
__global__ __launch_bounds__(256) void k4a_partial(
    const short* __restrict__ hpb, const float* __restrict__ sgate,
    float* __restrict__ partial)
{
    __shared__ float red[16];
    __shared__ float wlds[64];
    const int t = threadIdx.x;
    const int b = blockIdx.x >> 3;
    const int c0 = (blockIdx.x & 7) * 64;
    const int l = t & 63, w = t >> 6;
    const float L2E = 1.44269504088896f;

    const float s0 = sgate[b * C + t], s1 = sgate[b * C + 256 + t];
    float mx = fmaxf(s0, s1);
#pragma unroll
    for (int off = 1; off < 64; off <<= 1) mx = fmaxf(mx, __shfl_xor(mx, off));
    if (l == 0) red[w] = mx;
    __syncthreads();
    mx = fmaxf(fmaxf(red[0], red[1]), fmaxf(red[2], red[3]));
    float sum = exp2f((s0 - mx) * L2E) + exp2f((s1 - mx) * L2E);
#pragma unroll
    for (int off = 1; off < 64; off <<= 1) sum += __shfl_xor(sum, off);
    if (l == 0) red[8 + w] = sum;
    __syncthreads();
    sum = red[8] + red[9] + red[10] + red[11];
    const float inv = 1.f / sum;
    if (t < 64)
        wlds[t] = exp2f((sgate[b * C + c0 + t] - mx) * L2E) * inv;
    __syncthreads();

    float acc = 0.f;
    const short* base = hpb + ((size_t)b * C + c0) * DOUT + t;
#pragma unroll 4
    for (int c = 0; c < 64; ++c) acc += wlds[c] * bf2f(base[(size_t)c * DOUT]);
    partial[(size_t)blockIdx.x * DOUT + t] = acc;
}

// K4b: reduce the 8 chunk-partials per batch -> f32 out
__global__ __launch_bounds__(256) void k4b_reduce(
    const float* __restrict__ partial, float* __restrict__ out)
{
    const int t = threadIdx.x;
    const int b = blockIdx.x;
    float s = 0.f;
#pragma unroll
    for (int k = 0; k < 8; ++k)
        s += partial[(size_t)(b * 8 + k) * DOUT + t];
    out[b * DOUT + t] = s;
}

extern "C" void kernel_launch(void* const* d_in, const int* in_sizes, int n_in,
                              void* d_out, int out_size, void* d_ws, size_t ws_size,
                              hipStream_t stream) {
    const float* hsrc = (const float*)d_in[0];
    const float* Afc  = (const float*)d_in[1];
    const float* W    = (const float*)d_in[2];
    const float* avec = (const float*)d_in[3];
    const float* W1   = (const float*)d_in[4];
    const float* b1   = (const float*)d_in[5];
    const float* W2   = (const float*)d_in[6];
    const float* b2   = (const float*)d_in[7];

    char* ws = (char*)d_ws;
    short* whT   = (short*)(ws);                 // 16,777,216 B (fragment order)
    float* ei    = (float*)(ws + 16777216);      //    524,288 B
    float* ej    = (float*)(ws + 17301504);      //    524,288 B
    short* hpb   = (short*)(ws + 17825792);      // 16,777,216 B (bf16)
    float* sg    = (float*)(ws + 34603008);      //    131,072 B
    float* parts = (float*)(ws + 34734080);      //    524,288 B
    short* Wbf   = (short*)(ws + 35258368);      //    131,072 B
    short* W1bf  = (short*)(ws + 35389440);      //     32,768 B

    hipLaunchKernelGGL(k0_prep, dim3(40), dim3(256), 0, stream, W, W1, Wbf, W1bf);
    hipLaunchKernelGGL(k1_gemm, dim3(512), dim3(256), 0, stream, hsrc, Wbf, avec, whT, ei, ej);
    hipLaunchKernelGGL(k2_attn, dim3(2048), dim3(256), 0, stream, Afc, whT, ei, ej, hpb);
    hipLaunchKernelGGL(k3_gate, dim3(512), dim3(256), 0, stream, hpb, W1bf, b1, W2, b2, sg);
    hipLaunchKernelGGL(k4a_partial, dim3(512), dim3(256), 0, stream, hpb, sg, parts);
    hipLaunchKernelGGL(k4b_reduce, dim3(64), dim3(256), 0, stream, parts, (float*)d_out);
}